// Round 7
// baseline (71.989 us; speedup 1.0000x reference)
//
#include <hip/hip_runtime.h>
#include <math.h>

#define TT 1024
#define NN 64
#define CC 128
#define SS 128
#define CH 32          // steps per chunk
#define NCHUNK 32      // chunks covering t = 1..1024

// DPP controls (gfx9/CDNA encodings)
#define DPP_QP_XOR1   0xB1   // quad_perm [1,0,3,2]
#define DPP_QP_XOR2   0x4E   // quad_perm [2,3,0,1]
#define DPP_WAVE_SHR1 0x138  // whole-wave shift right by 1 lane
#define DPP_ROW_MIRR  0x140  // mirror within 16
#define DPP_HALF_MIRR 0x141  // mirror within 8
#define DPP_BCAST15   0x142  // lane15 -> next row
#define DPP_BCAST31   0x143  // lane31 -> upper half

template <int CTRL>
__device__ __forceinline__ float dpp_max_stage(float v) {
    int p = __builtin_amdgcn_update_dpp(__float_as_int(v), __float_as_int(v),
                                        CTRL, 0xF, 0xF, false);
    return fmaxf(v, __int_as_float(p));
}

// prev-lane value, lane 0 gets 0.0f (bound_ctrl: invalid lane -> 0)
__device__ __forceinline__ float dpp_shr1(float v) {
    int p = __builtin_amdgcn_update_dpp(0, __float_as_int(v),
                                        DPP_WAVE_SHR1, 0xF, 0xF, true);
    return __int_as_float(p);
}

// keep-alive pin: forces v to be materialized (and its load completed) here
__device__ __forceinline__ void pin4(const float4& v) {
    asm volatile("" :: "v"(v.x), "v"(v.y), "v"(v.z), "v"(v.w));
}

// Fused producer/consumer CTC forward scan. One block per batch element n.
// 5 waves: wave 0 = consumer (serial recurrence, alpha in registers),
// waves 1-4 = producers (gather + exp next chunk's emissions into a
// double-buffered LDS ring). The consumer batch-loads the ENTIRE chunk's
// emissions (24 x ds_read_b128) into pinned registers right after the
// barrier -- the asm pins are un-collapsible, so the 32-step compute runs
// with zero LDS waits. Recurrence math identical to verified rounds 2-6.
__global__ __launch_bounds__(320, 1) void ctc_scan(
    const float* __restrict__ lp,        // [T, N, C] fp32 log-softmax
    const int*   __restrict__ targets,   // [N, S]
    const int*   __restrict__ ilen,      // [N]
    const int*   __restrict__ tlen,      // [N]
    float*       __restrict__ v_out)     // [N] terminal log-alpha
{
    const int n    = blockIdx.x;
    const int tid  = threadIdx.x;
    const int wv   = tid >> 6;           // 0 = consumer, 1..4 = producers
    const int lane = tid & 63;

    __shared__ float4 s_e[2][CH / 2][64];   // 32 KiB
    __shared__ float4 s_pb4[2][CH / 4];     // 256 B

    const int tgA = targets[n * SS + 2 * lane];
    const int tgB = targets[n * SS + 2 * lane + 1];
    const float* lpn = lp + (size_t)n * CC;      // row t at lpn + t*NN*CC

    // ---------------- prologue: producers fill chunk 0 (t = 1..32) ----------
    if (wv != 0) {
        const int w = wv - 1;            // pairs k = w, w+4, w+8, w+12
        float va[8], vc[8];
#pragma unroll
        for (int i = 0; i < 4; ++i) {
            const int k = w + 4 * i;
            const float* rowa = lpn + (size_t)(1 + 2 * k) * (NN * CC);
            const float* rowb = lpn + (size_t)(2 + 2 * k) * (NN * CC);
            va[2*i]   = rowa[tgA]; vc[2*i]   = rowa[tgB];
            va[2*i+1] = rowb[tgA]; vc[2*i+1] = rowb[tgB];
        }
        float pbv = 0.f;
        if (lane < 8) pbv = lpn[(size_t)(1 + w * 8 + lane) * (NN * CC)];
#pragma unroll
        for (int i = 0; i < 4; ++i) {
            const int k = w + 4 * i;
            s_e[0][k][lane] = make_float4(__expf(va[2*i]),   __expf(vc[2*i]),
                                          __expf(va[2*i+1]), __expf(vc[2*i+1]));
        }
        if (lane < 8) ((float*)s_pb4[0])[w * 8 + lane] = __expf(pbv);
    }

    // consumer constants + t=0 init (reference: alpha0 zeros except s=0,1;
    // zeros in log domain == 1.0 linear)
    const int tgBm = (lane > 0) ? targets[n * SS + 2 * lane - 1] : -1;
    const float k1f = (lane > 0 && tgA != tgBm) ? 1.f : 0.f;
    const float k3f = (tgB != tgA) ? 1.f : 0.f;
    const int il    = ilen[n];
    const int vs    = 2 * tlen[n] - 1;   // odd, in [127, 255]
    const int vlane = vs >> 2;

    float a0 = 1.f, a1 = 1.f, a2 = 1.f, a3 = 1.f, ls = 0.f;
    if (wv == 0) {
        a0 = (lane == 0) ? __expf(lpn[0])   : 1.f;
        a1 = (lane == 0) ? __expf(lpn[tgA]) : 1.f;
    }
    float a3p = (lane == 0) ? 0.f : 1.f;
    float mr = 1.f, inv = 1.f;

    __syncthreads();

    // ---------------- main loop: 32 chunks of 32 steps ----------------------
    for (int cc = 0; cc < NCHUNK; ++cc) {
        const int b = cc & 1;
        if (wv == 0) {
            const int t0 = 1 + cc * CH;

            // batch-load the whole chunk's emissions into pinned registers
            float4 re[16], rp[8];
#pragma unroll
            for (int k = 0; k < 16; ++k) re[k] = s_e[b][k][lane];
#pragma unroll
            for (int m = 0; m < 8; ++m)  rp[m] = s_pb4[b][m];
#pragma unroll
            for (int k = 0; k < 16; ++k) pin4(re[k]);
#pragma unroll
            for (int m = 0; m < 8; ++m)  pin4(rp[m]);

            const bool cap = ((unsigned)(il - 1 - t0) < (unsigned)CH);

#pragma unroll
            for (int j = 0; j < CH; ++j) {
                const int m = j >> 2, c = j & 3;
                const float4 ea = re[2 * m], eb = re[2 * m + 1], pq = rp[m];
                const float cpa = (c==0)?ea.x:(c==1)?ea.z:(c==2)?eb.x:eb.z;
                const float cpc = (c==0)?ea.y:(c==1)?ea.w:(c==2)?eb.y:eb.w;
                const float cpb = (c==0)?pq.x:(c==1)?pq.y:(c==2)?pq.z:pq.w;

                float nb3 = fmaf(k3f, a1, a3 + a2) * cpc;
                float a3pn = dpp_shr1(nb3);
                float nb0 = (a0 + a3p) * cpb;
                float nb1 = fmaf(k1f, a3p, a0 + a1) * cpa;
                float nb2 = (a2 + a1) * cpb;

                // renorm every 8 steps: DPP butterfly spread one stage per
                // step, applied at jj==7 (stale-safe, values only shrink)
                const int jj = j & 7;
                if      (jj == 0) mr = fmaxf(fmaxf(nb0, nb1), fmaxf(nb2, nb3));
                else if (jj == 1) mr = dpp_max_stage<DPP_QP_XOR1>(mr);
                else if (jj == 2) mr = dpp_max_stage<DPP_QP_XOR2>(mr);
                else if (jj == 3) mr = dpp_max_stage<DPP_HALF_MIRR>(mr);
                else if (jj == 4) mr = dpp_max_stage<DPP_ROW_MIRR>(mr);
                else if (jj == 5) mr = dpp_max_stage<DPP_BCAST15>(mr);
                else if (jj == 6) mr = dpp_max_stage<DPP_BCAST31>(mr);
                else {
                    const float mru = __int_as_float(
                        __builtin_amdgcn_readlane(__float_as_int(mr), 63));
                    inv = 1.0f / mru;
                    ls += __logf(mru);
                    nb0 *= inv; nb1 *= inv; nb2 *= inv; nb3 *= inv;
                }

                if (cap) {
                    const int t = t0 + j;
                    if (t == il - 1 && lane == vlane)
                        v_out[n] = __logf((vs & 2) ? nb3 : nb1) + ls;
                }

                a0 = nb0; a1 = nb1; a2 = nb2; a3 = nb3;
                if (jj == 7) a3pn *= inv;
                a3p = a3pn;
            }
            // t = 1024 (last step of last chunk) is garbage from a clamped
            // row but is never captured (il-1 <= 1023).
        } else if (cc + 1 < NCHUNK) {
            // producers fill chunk cc+1 into the other buffer
            const int w  = wv - 1;
            const int b2 = (cc + 1) & 1;
            const int t0 = 1 + (cc + 1) * CH;
            float va[8], vc[8];
#pragma unroll
            for (int i = 0; i < 4; ++i) {
                const int k = w + 4 * i;
                int ta = t0 + 2 * k;     if (ta > TT - 1) ta = TT - 1;
                int tb = t0 + 2 * k + 1; if (tb > TT - 1) tb = TT - 1;
                const float* rowa = lpn + (size_t)ta * (NN * CC);
                const float* rowb = lpn + (size_t)tb * (NN * CC);
                va[2*i]   = rowa[tgA]; vc[2*i]   = rowa[tgB];
                va[2*i+1] = rowb[tgA]; vc[2*i+1] = rowb[tgB];
            }
            float pbv = 0.f;
            if (lane < 8) {
                int tp = t0 + w * 8 + lane; if (tp > TT - 1) tp = TT - 1;
                pbv = lpn[(size_t)tp * (NN * CC)];
            }
#pragma unroll
            for (int i = 0; i < 4; ++i) {
                const int k = w + 4 * i;
                s_e[b2][k][lane] = make_float4(__expf(va[2*i]),   __expf(vc[2*i]),
                                               __expf(va[2*i+1]), __expf(vc[2*i+1]));
            }
            if (lane < 8) ((float*)s_pb4[b2])[w * 8 + lane] = __expf(pbv);
        }
        __syncthreads();
    }
}

// loss = -logsumexp(v) over the 64 batch elements; single wave
__global__ void ctc_reduce(const float* __restrict__ v, float* __restrict__ out)
{
    const int lane = threadIdx.x;
    float x = v[lane];
    float m = x;
#pragma unroll
    for (int off = 32; off > 0; off >>= 1) m = fmaxf(m, __shfl_xor(m, off));
    float e = __expf(x - m);
#pragma unroll
    for (int off = 32; off > 0; off >>= 1) e += __shfl_xor(e, off);
    if (lane == 0) out[0] = -(m + __logf(e));
}

extern "C" void kernel_launch(void* const* d_in, const int* in_sizes, int n_in,
                              void* d_out, int out_size, void* d_ws, size_t ws_size,
                              hipStream_t stream) {
    const float* lp      = (const float*)d_in[0];
    const int*   targets = (const int*)d_in[1];
    const int*   ilen    = (const int*)d_in[2];
    const int*   tlen    = (const int*)d_in[3];

    float* v   = (float*)d_ws;    // 64 floats of scratch
    float* out = (float*)d_out;

    ctc_scan<<<NN, 320, 0, stream>>>(lp, targets, ilen, tlen, v);
    ctc_reduce<<<1, 64, 0, stream>>>(v, out);
}